// Round 1
// baseline (280.625 us; speedup 1.0000x reference)
//
#include <hip/hip_runtime.h>
#include <math.h>

#define B_ 8
#define L_ 1024
#define K_ 1024
#define D_ 128
#define S_ 16
#define DS_ (D_ * S_)

// ---------------------------------------------------------------------------
// Param precompute (double precision): ar/ai = Re/Im(Abar[d,s]), c = delta*Bp*Cp
// Written in [s][d] layout (s*128+d) so later LDS reads are bank-conflict-free.
// ---------------------------------------------------------------------------
__global__ void k_params(const float* __restrict__ log_Delta,
                         const float* __restrict__ Bp,
                         const float* __restrict__ Cp,
                         const float* __restrict__ log_A_real,
                         const float* __restrict__ A_imag,
                         float* __restrict__ par) {
    int i = blockIdx.x * blockDim.x + threadIdx.x;   // i = d*S + s
    if (i >= DS_) return;
    int d = i >> 4;
    int s = i & 15;
    double delta = exp((double)log_Delta[d]);
    double Are = -exp((double)log_A_real[i]);
    double Aim = (double)A_imag[i];
    double mag = exp(-1e-3 + delta * Are);
    double ang = delta * Aim;
    int o = s * D_ + d;
    par[o]            = (float)(mag * cos(ang));                       // ar
    par[DS_ + o]      = (float)(mag * sin(ang));                       // ai
    par[2 * DS_ + o]  = (float)(delta * (double)Bp[i] * (double)Cp[i]); // c
}

// ---------------------------------------------------------------------------
// Row norms of EigVecs: rn[b*L+l] = 1/||EigVecs[b,l,:]||
// ---------------------------------------------------------------------------
__global__ __launch_bounds__(256) void k_rownorm(const float* __restrict__ E,
                                                 float* __restrict__ rn) {
    int row = blockIdx.x;                       // 8192 rows
    const float4* p = (const float4*)(E + (size_t)row * K_);
    int t = threadIdx.x;
    float4 v = p[t];
    float s = v.x * v.x + v.y * v.y + v.z * v.z + v.w * v.w;
    #pragma unroll
    for (int off = 32; off > 0; off >>= 1) s += __shfl_down(s, off, 64);
    __shared__ float red[4];
    if ((t & 63) == 0) red[t >> 6] = s;
    __syncthreads();
    if (t == 0) {
        float tot = red[0] + red[1] + red[2] + red[3];
        rn[row] = 1.0f / sqrtf(tot);
    }
}

// ---------------------------------------------------------------------------
// In-proj: u = x1 * silu(z), h = BN(x) @ W_in + b_in. 16 rows/block, 512 blocks.
// Thread t: column j = t&127 (both halves j and j+128), rows half*8..+8.
// ---------------------------------------------------------------------------
__global__ __launch_bounds__(256) void k_inproj(
    const float* __restrict__ x, const float* __restrict__ g,
    const float* __restrict__ beta, const float* __restrict__ mean,
    const float* __restrict__ var, const float* __restrict__ W_in,
    const float* __restrict__ b_in, float* __restrict__ u) {
    __shared__ float xb[16][128];
    int row0 = blockIdx.x * 16;
    int t = threadIdx.x;
    #pragma unroll
    for (int p = 0; p < 8; ++p) {
        int idx = t + p * 256;
        int dd = idx & 127, r = idx >> 7;
        float sc = g[dd] / sqrtf(var[dd] + 1e-5f);
        xb[r][dd] = (x[(size_t)(row0 + r) * D_ + dd] - mean[dd]) * sc + beta[dd];
    }
    __syncthreads();
    int j = t & 127, half = t >> 7;
    float acc1[8], acc2[8];
    #pragma unroll
    for (int r = 0; r < 8; ++r) { acc1[r] = 0.f; acc2[r] = 0.f; }
    for (int dd = 0; dd < 128; ++dd) {
        float w1 = W_in[dd * 256 + j];
        float w2 = W_in[dd * 256 + 128 + j];
        #pragma unroll
        for (int r = 0; r < 8; ++r) {
            float xv = xb[half * 8 + r][dd];
            acc1[r] = fmaf(xv, w1, acc1[r]);
            acc2[r] = fmaf(xv, w2, acc2[r]);
        }
    }
    float b1 = b_in[j], b2 = b_in[128 + j];
    #pragma unroll
    for (int r = 0; r < 8; ++r) {
        float x1 = acc1[r] + b1;
        float z  = acc2[r] + b2;
        float sig = 1.0f / (1.0f + __expf(-z));
        u[(size_t)(row0 + half * 8 + r) * D_ + j] = x1 * z * sig;
    }
}

// ---------------------------------------------------------------------------
// QTX GEMM + complex-ratio epilogue -> G[b,k,d] = QTX[b,k,d] * w[b,k,d]
// Block: batch b, 32 k's x 128 d's. 512 threads: tx=d-lane (d=tx+32j), ty=k/2.
// ---------------------------------------------------------------------------
__global__ __launch_bounds__(512) void k_qtx_g(
    const float* __restrict__ E, const float* __restrict__ rn,
    const float* __restrict__ u, const float* __restrict__ EigVals,
    const float* __restrict__ par, float* __restrict__ G) {
    int b = blockIdx.x >> 5;
    int k0 = (blockIdx.x & 31) * 32;
    int t = threadIdx.x;
    int tx = t & 31, ty = t >> 5;            // ty in [0,16)
    __shared__ float Es[32][32];             // [li][kj]
    __shared__ float Us[32][128];            // [li][d]
    __shared__ float parS[3 * DS_];          // ar | ai | c, each [s][d]
    for (int i = t; i < 3 * DS_; i += 512) parS[i] = par[i];
    float acc[2][4];
    #pragma unroll
    for (int i = 0; i < 2; ++i)
        #pragma unroll
        for (int j = 0; j < 4; ++j) acc[i][j] = 0.f;
    const float* Eb = E + (size_t)b * L_ * K_;
    const float* ub = u + (size_t)b * L_ * D_;
    for (int l0 = 0; l0 < L_; l0 += 32) {
        #pragma unroll
        for (int p = 0; p < 2; ++p) {
            int li = (t >> 5) + p * 16, kj = t & 31;
            Es[li][kj] = Eb[(size_t)(l0 + li) * K_ + k0 + kj] * rn[b * L_ + l0 + li];
        }
        #pragma unroll
        for (int p = 0; p < 2; ++p) {
            int f4 = t + p * 512;            // 1024 float4s total
            int d4 = f4 & 31, li = f4 >> 5;
            *(float4*)&Us[li][d4 * 4] =
                ((const float4*)(ub + (size_t)(l0 + li) * D_))[d4];
        }
        __syncthreads();
        #pragma unroll 8
        for (int li = 0; li < 32; ++li) {
            float a0 = Es[li][ty * 2], a1 = Es[li][ty * 2 + 1];
            float u0 = Us[li][tx], u1 = Us[li][tx + 32];
            float u2 = Us[li][tx + 64], u3 = Us[li][tx + 96];
            acc[0][0] = fmaf(a0, u0, acc[0][0]);
            acc[0][1] = fmaf(a0, u1, acc[0][1]);
            acc[0][2] = fmaf(a0, u2, acc[0][2]);
            acc[0][3] = fmaf(a0, u3, acc[0][3]);
            acc[1][0] = fmaf(a1, u0, acc[1][0]);
            acc[1][1] = fmaf(a1, u1, acc[1][1]);
            acc[1][2] = fmaf(a1, u2, acc[1][2]);
            acc[1][3] = fmaf(a1, u3, acc[1][3]);
        }
        __syncthreads();
    }
    // epilogue: w[b,k,d] = sum_s c * Re(lamA/(1-lamA)), lamA = ev*(ar+i*ai)
    float ev0 = 1.0f - EigVals[b * K_ + k0 + ty * 2];
    float ev1 = 1.0f - EigVals[b * K_ + k0 + ty * 2 + 1];
    size_t gb = ((size_t)b * K_ + k0 + ty * 2) * D_;
    #pragma unroll
    for (int j = 0; j < 4; ++j) {
        int dd = tx + 32 * j;
        float w0 = 0.f, w1 = 0.f;
        #pragma unroll
        for (int s = 0; s < S_; ++s) {
            float ar = parS[s * D_ + dd];
            float ai = parS[DS_ + s * D_ + dd];
            float c  = parS[2 * DS_ + s * D_ + dd];
            {
                float a = ev0 * ar, bi = ev0 * ai;
                float oma = 1.0f - a;           // exact (Sterbenz) when a in [0.5,1]
                float b2 = bi * bi;
                float num = fmaf(a, oma, -b2);  // a(1-a) - b^2
                float den = fmaf(oma, oma, b2); // (1-a)^2 + b^2  (no cancellation)
                float r = __builtin_amdgcn_rcpf(den);
                r = r * (2.0f - den * r);       // Newton -> ~1 ulp
                w0 = fmaf(c, num * r, w0);
            }
            {
                float a = ev1 * ar, bi = ev1 * ai;
                float oma = 1.0f - a;
                float b2 = bi * bi;
                float num = fmaf(a, oma, -b2);
                float den = fmaf(oma, oma, b2);
                float r = __builtin_amdgcn_rcpf(den);
                r = r * (2.0f - den * r);
                w1 = fmaf(c, num * r, w1);
            }
        }
        G[gb + dd]      = acc[0][j] * w0;
        G[gb + D_ + dd] = acc[1][j] * w1;
    }
}

// ---------------------------------------------------------------------------
// yssm = Q @ G, then y = silu(yssm) @ W_out + b_out (fused).
// Block: batch b, 32 l's x 128 d's. 512 threads.
// ---------------------------------------------------------------------------
__global__ __launch_bounds__(512) void k_yout(
    const float* __restrict__ E, const float* __restrict__ rn,
    const float* __restrict__ G, const float* __restrict__ W_out,
    const float* __restrict__ b_out, float* __restrict__ y) {
    int b = blockIdx.x >> 5;
    int l0 = (blockIdx.x & 31) * 32;
    int t = threadIdx.x;
    int tx = t & 31, ty = t >> 5;            // ty in [0,16)
    __shared__ float Es[32][33];             // [li][kj], padded
    __shared__ float Gs[32][128];            // [kj][d]
    __shared__ float Ys[32][128];            // silu(yssm) tile
    float acc[2][4];
    #pragma unroll
    for (int i = 0; i < 2; ++i)
        #pragma unroll
        for (int j = 0; j < 4; ++j) acc[i][j] = 0.f;
    const float* Eb = E + (size_t)b * L_ * K_;
    for (int k0 = 0; k0 < K_; k0 += 32) {
        #pragma unroll
        for (int p = 0; p < 2; ++p) {
            int li = (t >> 5) + p * 16, kj = t & 31;
            Es[li][kj] = Eb[(size_t)(l0 + li) * K_ + k0 + kj];
        }
        #pragma unroll
        for (int p = 0; p < 2; ++p) {
            int f4 = t + p * 512;
            int d4 = f4 & 31, kj = f4 >> 5;
            *(float4*)&Gs[kj][d4 * 4] =
                ((const float4*)(G + ((size_t)b * K_ + k0 + kj) * D_))[d4];
        }
        __syncthreads();
        #pragma unroll 8
        for (int kj = 0; kj < 32; ++kj) {
            float a0 = Es[ty * 2][kj], a1 = Es[ty * 2 + 1][kj];
            float g0 = Gs[kj][tx], g1 = Gs[kj][tx + 32];
            float g2 = Gs[kj][tx + 64], g3 = Gs[kj][tx + 96];
            acc[0][0] = fmaf(a0, g0, acc[0][0]);
            acc[0][1] = fmaf(a0, g1, acc[0][1]);
            acc[0][2] = fmaf(a0, g2, acc[0][2]);
            acc[0][3] = fmaf(a0, g3, acc[0][3]);
            acc[1][0] = fmaf(a1, g0, acc[1][0]);
            acc[1][1] = fmaf(a1, g1, acc[1][1]);
            acc[1][2] = fmaf(a1, g2, acc[1][2]);
            acc[1][3] = fmaf(a1, g3, acc[1][3]);
        }
        __syncthreads();
    }
    #pragma unroll
    for (int i = 0; i < 2; ++i) {
        int l = ty * 2 + i;
        float r = rn[b * L_ + l0 + l];
        #pragma unroll
        for (int j = 0; j < 4; ++j) {
            float v = acc[i][j] * r;
            float sig = 1.0f / (1.0f + __expf(-v));
            Ys[l][tx + 32 * j] = v * sig;
        }
    }
    __syncthreads();
    // out-proj: y[l, j2] = sum_d Ys[l][d] * W_out[d][j2] + b_out[j2]
    int j2 = t & 127, q = t >> 7;            // q in [0,4), 8 rows each
    float acc2[8];
    #pragma unroll
    for (int r = 0; r < 8; ++r) acc2[r] = 0.f;
    for (int dd = 0; dd < 128; ++dd) {
        float wv = W_out[dd * 128 + j2];
        #pragma unroll
        for (int r = 0; r < 8; ++r)
            acc2[r] = fmaf(Ys[q * 8 + r][dd], wv, acc2[r]);
    }
    float bo = b_out[j2];
    #pragma unroll
    for (int r = 0; r < 8; ++r)
        y[((size_t)b * L_ + l0 + q * 8 + r) * D_ + j2] = acc2[r] + bo;
}

// ---------------------------------------------------------------------------
extern "C" void kernel_launch(void* const* d_in, const int* in_sizes, int n_in,
                              void* d_out, int out_size, void* d_ws, size_t ws_size,
                              hipStream_t stream) {
    const float* x          = (const float*)d_in[0];
    // d_in[1] = attn_mask (unused by the reference math)
    const float* EigVecs    = (const float*)d_in[2];
    const float* EigVals    = (const float*)d_in[3];
    const float* bn_gamma   = (const float*)d_in[4];
    const float* bn_beta    = (const float*)d_in[5];
    const float* bn_mean    = (const float*)d_in[6];
    const float* bn_var     = (const float*)d_in[7];
    const float* W_in       = (const float*)d_in[8];
    const float* b_in       = (const float*)d_in[9];
    const float* log_Delta  = (const float*)d_in[10];
    const float* Bp         = (const float*)d_in[11];
    const float* Cp         = (const float*)d_in[12];
    const float* log_A_real = (const float*)d_in[13];
    const float* A_imag     = (const float*)d_in[14];
    const float* W_out      = (const float*)d_in[15];
    const float* b_out      = (const float*)d_in[16];

    float* y  = (float*)d_out;
    float* ws = (float*)d_ws;
    float* rn  = ws;                          // 8192 floats
    float* G   = ws + 8192;                   // 1,048,576 floats
    float* par = ws + 8192 + (size_t)B_ * K_ * D_;  // 6144 floats
    float* u   = y;                           // stage u in d_out (overwritten later)

    k_params<<<dim3(8), dim3(256), 0, stream>>>(log_Delta, Bp, Cp, log_A_real, A_imag, par);
    k_rownorm<<<dim3(B_ * L_), dim3(256), 0, stream>>>(EigVecs, rn);
    k_inproj<<<dim3(B_ * L_ / 16), dim3(256), 0, stream>>>(
        x, bn_gamma, bn_beta, bn_mean, bn_var, W_in, b_in, u);
    k_qtx_g<<<dim3(B_ * (K_ / 32)), dim3(512), 0, stream>>>(
        EigVecs, rn, u, EigVals, par, G);
    k_yout<<<dim3(B_ * (L_ / 32)), dim3(512), 0, stream>>>(
        EigVecs, rn, G, W_out, b_out, y);
}

// Round 2
// 215.101 us; speedup vs baseline: 1.3046x; 1.3046x over previous
//
#include <hip/hip_runtime.h>
#include <math.h>

#define B_ 8
#define L_ 1024
#define K_ 1024
#define D_ 128
#define S_ 16
#define DS_ (D_ * S_)

// ---------------------------------------------------------------------------
// Param precompute (double precision): ar/ai = Re/Im(Abar[d,s]), c = delta*Bp*Cp
// Layout [s][d] (s*128+d).
// ---------------------------------------------------------------------------
__global__ void k_params(const float* __restrict__ log_Delta,
                         const float* __restrict__ Bp,
                         const float* __restrict__ Cp,
                         const float* __restrict__ log_A_real,
                         const float* __restrict__ A_imag,
                         float* __restrict__ par) {
    int i = blockIdx.x * blockDim.x + threadIdx.x;   // i = d*S + s
    if (i >= DS_) return;
    int d = i >> 4;
    int s = i & 15;
    double delta = exp((double)log_Delta[d]);
    double Are = -exp((double)log_A_real[i]);
    double Aim = (double)A_imag[i];
    double mag = exp(-1e-3 + delta * Are);
    double ang = delta * Aim;
    int o = s * D_ + d;
    par[o]            = (float)(mag * cos(ang));
    par[DS_ + o]      = (float)(mag * sin(ang));
    par[2 * DS_ + o]  = (float)(delta * (double)Bp[i] * (double)Cp[i]);
}

// ---------------------------------------------------------------------------
__global__ __launch_bounds__(256) void k_rownorm(const float* __restrict__ E,
                                                 float* __restrict__ rn) {
    int row = blockIdx.x;
    const float4* p = (const float4*)(E + (size_t)row * K_);
    int t = threadIdx.x;
    float4 v = p[t];
    float s = v.x * v.x + v.y * v.y + v.z * v.z + v.w * v.w;
    #pragma unroll
    for (int off = 32; off > 0; off >>= 1) s += __shfl_down(s, off, 64);
    __shared__ float red[4];
    if ((t & 63) == 0) red[t >> 6] = s;
    __syncthreads();
    if (t == 0) rn[row] = 1.0f / sqrtf(red[0] + red[1] + red[2] + red[3]);
}

// ---------------------------------------------------------------------------
// In-proj: u = x1 * silu(z). 16 rows/block, 512 blocks of 256.
// ---------------------------------------------------------------------------
__global__ __launch_bounds__(256) void k_inproj(
    const float* __restrict__ x, const float* __restrict__ g,
    const float* __restrict__ beta, const float* __restrict__ mean,
    const float* __restrict__ var, const float* __restrict__ W_in,
    const float* __restrict__ b_in, float* __restrict__ u) {
    __shared__ float xb[16][128];
    int row0 = blockIdx.x * 16;
    int t = threadIdx.x;
    #pragma unroll
    for (int p = 0; p < 8; ++p) {
        int idx = t + p * 256;
        int dd = idx & 127, r = idx >> 7;
        float sc = g[dd] / sqrtf(var[dd] + 1e-5f);
        xb[r][dd] = (x[(size_t)(row0 + r) * D_ + dd] - mean[dd]) * sc + beta[dd];
    }
    __syncthreads();
    int j = t & 127, half = t >> 7;
    float acc1[8], acc2[8];
    #pragma unroll
    for (int r = 0; r < 8; ++r) { acc1[r] = 0.f; acc2[r] = 0.f; }
    #pragma unroll 4
    for (int dd = 0; dd < 128; ++dd) {
        float w1 = W_in[dd * 256 + j];
        float w2 = W_in[dd * 256 + 128 + j];
        #pragma unroll
        for (int r = 0; r < 8; ++r) {
            float xv = xb[half * 8 + r][dd];
            acc1[r] = fmaf(xv, w1, acc1[r]);
            acc2[r] = fmaf(xv, w2, acc2[r]);
        }
    }
    float b1 = b_in[j], b2 = b_in[128 + j];
    #pragma unroll
    for (int r = 0; r < 8; ++r) {
        float x1 = acc1[r] + b1;
        float z  = acc2[r] + b2;
        float sig = 1.0f / (1.0f + __expf(-z));
        u[(size_t)(row0 + half * 8 + r) * D_ + j] = x1 * z * sig;
    }
}

// ---------------------------------------------------------------------------
// GEMM1 partials: P[nl][b][k][d] = sum_{l in slice} Q[l,k]*u[l,d]
// Block: 128k x 128d tile, 256 threads, 8x8 per thread. grid = B*8*nsl.
// ---------------------------------------------------------------------------
__global__ __launch_bounds__(256) void k_qtx(
    const float* __restrict__ E, const float* __restrict__ rn,
    const float* __restrict__ u, float* __restrict__ P, int nsl) {
    int slice = L_ / nsl;
    int bx = blockIdx.x;
    int nl = bx % nsl;
    int kt = (bx / nsl) & 7;
    int b  = bx / (nsl * 8);
    int k0 = kt * 128;
    int lbeg = nl * slice;
    __shared__ float Es[32][128];
    __shared__ float Us[32][128];
    int t = threadIdx.x;
    int tx = t & 15, ty = t >> 4;
    float acc[8][8];
    #pragma unroll
    for (int i = 0; i < 8; ++i)
        #pragma unroll
        for (int j = 0; j < 8; ++j) acc[i][j] = 0.f;
    const float* Eb = E + (size_t)b * L_ * K_;
    const float* ub = u + (size_t)b * L_ * D_;
    for (int l0 = lbeg; l0 < lbeg + slice; l0 += 32) {
        #pragma unroll
        for (int r = 0; r < 4; ++r) {
            int idx = t + r * 256;
            int li = idx >> 5, c4 = (idx & 31) * 4;
            float rnv = rn[b * L_ + l0 + li];
            float4 e = *(const float4*)&Eb[(size_t)(l0 + li) * K_ + k0 + c4];
            e.x *= rnv; e.y *= rnv; e.z *= rnv; e.w *= rnv;
            *(float4*)&Es[li][c4] = e;
            *(float4*)&Us[li][c4] = *(const float4*)&ub[(size_t)(l0 + li) * D_ + c4];
        }
        __syncthreads();
        #pragma unroll 4
        for (int li = 0; li < 32; ++li) {
            float4 A0 = *(float4*)&Es[li][ty * 4];
            float4 A1 = *(float4*)&Es[li][ty * 4 + 64];
            float4 B0 = *(float4*)&Us[li][tx * 4];
            float4 B1 = *(float4*)&Us[li][tx * 4 + 64];
            float av[8] = {A0.x, A0.y, A0.z, A0.w, A1.x, A1.y, A1.z, A1.w};
            float bv[8] = {B0.x, B0.y, B0.z, B0.w, B1.x, B1.y, B1.z, B1.w};
            #pragma unroll
            for (int i = 0; i < 8; ++i)
                #pragma unroll
                for (int j = 0; j < 8; ++j)
                    acc[i][j] = fmaf(av[i], bv[j], acc[i][j]);
        }
        __syncthreads();
    }
    float* Pb = P + (((size_t)nl * B_ + b) * K_ + k0) * D_;
    #pragma unroll
    for (int i = 0; i < 8; ++i) {
        int kk = ty * 4 + (i >> 2) * 64 + (i & 3);
        float4 v0 = {acc[i][0], acc[i][1], acc[i][2], acc[i][3]};
        float4 v1 = {acc[i][4], acc[i][5], acc[i][6], acc[i][7]};
        *(float4*)&Pb[(size_t)kk * D_ + tx * 4]      = v0;
        *(float4*)&Pb[(size_t)kk * D_ + tx * 4 + 64] = v1;
    }
}

// ---------------------------------------------------------------------------
// Reduce partials + complex-ratio epilogue -> G[b,k,d]
// ---------------------------------------------------------------------------
__global__ __launch_bounds__(256) void k_gepi(
    const float* __restrict__ P, const float* __restrict__ EigVals,
    const float* __restrict__ par, float* __restrict__ G, int nsl) {
    __shared__ float parS[3 * DS_];
    int t = threadIdx.x;
    for (int i = t; i < 3 * DS_; i += 256) parS[i] = par[i];
    __syncthreads();
    int row = blockIdx.x * 8 + (t >> 5);     // b*K + k
    int tx = t & 31;
    int d0 = tx * 4;
    float4 sum = {0.f, 0.f, 0.f, 0.f};
    for (int n = 0; n < nsl; ++n) {
        float4 v = *(const float4*)&P[((size_t)n * (B_ * K_) + row) * D_ + d0];
        sum.x += v.x; sum.y += v.y; sum.z += v.z; sum.w += v.w;
    }
    float ev = 1.0f - EigVals[row];
    float q[4] = {sum.x, sum.y, sum.z, sum.w};
    float o[4];
    #pragma unroll
    for (int c = 0; c < 4; ++c) {
        int dd = d0 + c;
        float w = 0.f;
        #pragma unroll
        for (int s = 0; s < S_; ++s) {
            float ar = parS[s * D_ + dd];
            float ai = parS[DS_ + s * D_ + dd];
            float cc = parS[2 * DS_ + s * D_ + dd];
            float a = ev * ar, bi = ev * ai;
            float oma = 1.0f - a;            // exact (Sterbenz) for a in [0.5,1]
            float b2 = bi * bi;
            float num = fmaf(a, oma, -b2);
            float den = fmaf(oma, oma, b2);  // no cancellation
            float r = __builtin_amdgcn_rcpf(den);
            r = r * (2.0f - den * r);
            w = fmaf(cc, num * r, w);
        }
        o[c] = q[c] * w;
    }
    float4 ov = {o[0], o[1], o[2], o[3]};
    *(float4*)&G[(size_t)row * D_ + d0] = ov;
}

// ---------------------------------------------------------------------------
// GEMM2 partials: Py[nk][b][l][d] = sum_{k in slice} Q_raw[l,k]*G[k,d]
// (rn folded in k_out). Block: 128l x 128d tile, 256 threads. grid = B*8*nsl.
// ---------------------------------------------------------------------------
__global__ __launch_bounds__(256) void k_yssm(
    const float* __restrict__ E, const float* __restrict__ G,
    float* __restrict__ Py, int nsl) {
    int slice = K_ / nsl;
    int bx = blockIdx.x;
    int nk = bx % nsl;
    int lt = (bx / nsl) & 7;
    int b  = bx / (nsl * 8);
    int l0t = lt * 128;
    int kbeg = nk * slice;
    __shared__ float Qt[32][132];            // [kk][l], pad 132 (rows stay 16B-aligned)
    __shared__ float Gs[32][128];            // [kk][d]
    int t = threadIdx.x;
    int tx = t & 15, ty = t >> 4;
    float acc[8][8];
    #pragma unroll
    for (int i = 0; i < 8; ++i)
        #pragma unroll
        for (int j = 0; j < 8; ++j) acc[i][j] = 0.f;
    const float* Eb = E + (size_t)b * L_ * K_;
    const float* Gb = G + (size_t)b * K_ * D_;
    for (int k0 = kbeg; k0 < kbeg + slice; k0 += 32) {
        #pragma unroll
        for (int r = 0; r < 4; ++r) {
            int idx = t + r * 256;
            int li = idx >> 3;               // [0,128)
            int kq = (idx & 7) * 4;          // {0,...,28}
            float4 q = *(const float4*)&Eb[(size_t)(l0t + li) * K_ + k0 + kq];
            Qt[kq + 0][li] = q.x;
            Qt[kq + 1][li] = q.y;
            Qt[kq + 2][li] = q.z;
            Qt[kq + 3][li] = q.w;
            int kk = idx >> 5, d4 = (idx & 31) * 4;
            *(float4*)&Gs[kk][d4] = *(const float4*)&Gb[(size_t)(k0 + kk) * D_ + d4];
        }
        __syncthreads();
        #pragma unroll 4
        for (int kk = 0; kk < 32; ++kk) {
            float4 A0 = *(float4*)&Qt[kk][ty * 4];
            float4 A1 = *(float4*)&Qt[kk][ty * 4 + 64];
            float4 B0 = *(float4*)&Gs[kk][tx * 4];
            float4 B1 = *(float4*)&Gs[kk][tx * 4 + 64];
            float av[8] = {A0.x, A0.y, A0.z, A0.w, A1.x, A1.y, A1.z, A1.w};
            float bv[8] = {B0.x, B0.y, B0.z, B0.w, B1.x, B1.y, B1.z, B1.w};
            #pragma unroll
            for (int i = 0; i < 8; ++i)
                #pragma unroll
                for (int j = 0; j < 8; ++j)
                    acc[i][j] = fmaf(av[i], bv[j], acc[i][j]);
        }
        __syncthreads();
    }
    float* Pb = Py + ((size_t)nk * B_ + b) * (size_t)L_ * D_ + (size_t)l0t * D_;
    #pragma unroll
    for (int i = 0; i < 8; ++i) {
        int lr = ty * 4 + (i >> 2) * 64 + (i & 3);
        float4 v0 = {acc[i][0], acc[i][1], acc[i][2], acc[i][3]};
        float4 v1 = {acc[i][4], acc[i][5], acc[i][6], acc[i][7]};
        *(float4*)&Pb[(size_t)lr * D_ + tx * 4]      = v0;
        *(float4*)&Pb[(size_t)lr * D_ + tx * 4 + 64] = v1;
    }
}

// ---------------------------------------------------------------------------
// Reduce Py, *rn, silu, out-proj -> y. 16 rows/block, 512 blocks.
// ---------------------------------------------------------------------------
__global__ __launch_bounds__(256) void k_out(
    const float* __restrict__ Py, const float* __restrict__ rn,
    const float* __restrict__ W_out, const float* __restrict__ b_out,
    float* __restrict__ y, int nsl) {
    __shared__ float Ys[16][128];
    int row0 = blockIdx.x * 16;              // global row = b*L + l
    int t = threadIdx.x;
    #pragma unroll
    for (int r = 0; r < 2; ++r) {
        int idx = t + r * 256;               // [0,512) float4s
        int rr = idx >> 5, d4 = (idx & 31) * 4;
        int grow = row0 + rr;
        float4 s = {0.f, 0.f, 0.f, 0.f};
        for (int n = 0; n < nsl; ++n) {
            float4 v = *(const float4*)&Py[((size_t)n * (B_ * L_) + grow) * D_ + d4];
            s.x += v.x; s.y += v.y; s.z += v.z; s.w += v.w;
        }
        float rv = rn[grow];
        float o[4] = {s.x * rv, s.y * rv, s.z * rv, s.w * rv};
        #pragma unroll
        for (int c = 0; c < 4; ++c) {
            float sig = 1.0f / (1.0f + __expf(-o[c]));
            Ys[rr][d4 + c] = o[c] * sig;
        }
    }
    __syncthreads();
    int j = t & 127, h = t >> 7;             // h in {0,1}: 8 rows each
    float a2[8];
    #pragma unroll
    for (int r = 0; r < 8; ++r) a2[r] = 0.f;
    for (int dd = 0; dd < 128; dd += 4) {
        float w0 = W_out[(dd + 0) * 128 + j];
        float w1 = W_out[(dd + 1) * 128 + j];
        float w2 = W_out[(dd + 2) * 128 + j];
        float w3 = W_out[(dd + 3) * 128 + j];
        #pragma unroll
        for (int r = 0; r < 8; ++r) {
            float4 yv = *(float4*)&Ys[h * 8 + r][dd];
            a2[r] = fmaf(yv.x, w0, a2[r]);
            a2[r] = fmaf(yv.y, w1, a2[r]);
            a2[r] = fmaf(yv.z, w2, a2[r]);
            a2[r] = fmaf(yv.w, w3, a2[r]);
        }
    }
    float bo = b_out[j];
    #pragma unroll
    for (int r = 0; r < 8; ++r)
        y[(size_t)(row0 + h * 8 + r) * D_ + j] = a2[r] + bo;
}

// ---------------------------------------------------------------------------
extern "C" void kernel_launch(void* const* d_in, const int* in_sizes, int n_in,
                              void* d_out, int out_size, void* d_ws, size_t ws_size,
                              hipStream_t stream) {
    const float* x          = (const float*)d_in[0];
    const float* EigVecs    = (const float*)d_in[2];
    const float* EigVals    = (const float*)d_in[3];
    const float* bn_gamma   = (const float*)d_in[4];
    const float* bn_beta    = (const float*)d_in[5];
    const float* bn_mean    = (const float*)d_in[6];
    const float* bn_var     = (const float*)d_in[7];
    const float* W_in       = (const float*)d_in[8];
    const float* b_in       = (const float*)d_in[9];
    const float* log_Delta  = (const float*)d_in[10];
    const float* Bp         = (const float*)d_in[11];
    const float* Cp         = (const float*)d_in[12];
    const float* log_A_real = (const float*)d_in[13];
    const float* A_imag     = (const float*)d_in[14];
    const float* W_out      = (const float*)d_in[15];
    const float* b_out      = (const float*)d_in[16];

    float* y  = (float*)d_out;
    float* ws = (float*)d_ws;
    float* rn  = ws;                                 // 8192 floats
    float* par = ws + 8192;                          // 6144 floats
    float* G   = ws + 16384;                         // 1,048,576 floats
    float* P   = ws + 16384 + (size_t)B_ * K_ * D_;  // nsl * 1,048,576 floats
    float* u   = y;                                  // stage u in d_out

    // largest slice count whose partial buffers fit the workspace
    int nsl = 8;
    while (nsl > 1) {
        size_t need = ((size_t)16384 + (size_t)B_ * K_ * D_ * (size_t)(1 + nsl)) * 4;
        if (need <= ws_size) break;
        nsl >>= 1;
    }

    k_params<<<dim3(8), dim3(256), 0, stream>>>(log_Delta, Bp, Cp, log_A_real, A_imag, par);
    k_rownorm<<<dim3(B_ * L_), dim3(256), 0, stream>>>(EigVecs, rn);
    k_inproj<<<dim3(B_ * L_ / 16), dim3(256), 0, stream>>>(
        x, bn_gamma, bn_beta, bn_mean, bn_var, W_in, b_in, u);
    k_qtx<<<dim3(B_ * 8 * nsl), dim3(256), 0, stream>>>(EigVecs, rn, u, P, nsl);
    k_gepi<<<dim3(B_ * K_ / 8), dim3(256), 0, stream>>>(P, EigVals, par, G, nsl);
    // Py reuses P (P fully consumed by k_gepi before k_yssm writes)
    k_yssm<<<dim3(B_ * 8 * nsl), dim3(256), 0, stream>>>(EigVecs, G, P, nsl);
    k_out<<<dim3(B_ * L_ / 16), dim3(256), 0, stream>>>(P, rn, W_out, b_out, y, nsl);
}